// Round 6
// baseline (333.382 us; speedup 1.0000x reference)
//
#include <hip/hip_runtime.h>

#define TSEQ 2048
#define BB 4
#define CDIM 1024
#define NH 16
#define HD 64
#define MR (TSEQ*BB)   // 8192 rows
#define C2SCALE 0.045084220f   // log2(e)/sqrt(CDIM) = log2(e)/32

typedef __attribute__((ext_vector_type(8))) short sh8;   // 8 bf16 = 4 VGPRs
typedef __attribute__((ext_vector_type(4))) short sh4;   // 4 bf16
typedef __attribute__((ext_vector_type(4))) float f4;    // MFMA C/D
typedef __attribute__((ext_vector_type(4))) unsigned int u32x4;

__device__ __forceinline__ unsigned short f2bf(float x){
  unsigned u = __builtin_bit_cast(unsigned, x);
  u += 0x7fffu + ((u>>16)&1u);          // round-to-nearest-even
  return (unsigned short)(u>>16);
}

// pack two floats -> dword of 2 bf16 (lo = a, hi = b), single VALU op
__device__ __forceinline__ unsigned cvtpk(float a, float b){
  unsigned r;
  asm("v_cvt_pk_bf16_f32 %0, %1, %2" : "=v"(r) : "v"(a), "v"(b));
  return r;
}

__device__ __forceinline__ void gll16(const unsigned short* g, unsigned short* l){
  __builtin_amdgcn_global_load_lds(
      (const __attribute__((address_space(1))) unsigned int*)g,
      (__attribute__((address_space(3))) unsigned int*)l, 16, 0, 0);
}

// ---------------- fp32 -> bf16 conversion, fused ----------------
__global__ void conv_x(const float* __restrict__ a, const float* __restrict__ b,
                       unsigned short* __restrict__ ya, unsigned short* __restrict__ yb){
  const float* s = blockIdx.y ? b : a;
  unsigned short* d = blockIdx.y ? yb : ya;
  int i = (blockIdx.x*256 + threadIdx.x)*4;
  f4 v = *(const f4*)(s+i);
  sh4 o;
  o.x = (short)f2bf(v.x); o.y = (short)f2bf(v.y);
  o.z = (short)f2bf(v.z); o.w = (short)f2bf(v.w);
  *(sh4*)(d+i) = o;
}

__global__ void conv_w(const float* __restrict__ w0, const float* __restrict__ w1,
                       const float* __restrict__ w2, const float* __restrict__ w3,
                       unsigned short* __restrict__ y0, unsigned short* __restrict__ y1,
                       unsigned short* __restrict__ y2, unsigned short* __restrict__ y3){
  const float* s; unsigned short* d;
  switch(blockIdx.y){
    case 0: s=w0; d=y0; break;
    case 1: s=w1; d=y1; break;
    case 2: s=w2; d=y2; break;
    default: s=w3; d=y3; break;
  }
  int i = (blockIdx.x*256 + threadIdx.x)*4;
  f4 v = *(const f4*)(s+i);
  sh4 o;
  o.x = (short)f2bf(v.x); o.y = (short)f2bf(v.y);
  o.z = (short)f2bf(v.z); o.w = (short)f2bf(v.w);
  *(sh4*)(d+i) = o;
}

// ============ m201-style 8-phase GEMM core (round-6) ============
// BM=BN=256, BK=64, 512 threads = 8 waves (2M x 4N), per-wave 128x64.
// LDS: 2 full-tile buffers x (A 256x64 + B 256x64) x 2B = 128KB, 1 block/CU.
// Per K-tile: 4 phases. Phase p (1..4):
//   reads: A-quarter p (4 ds_read_b128) [+ ALL B (8 b128) -> regs at p=1]
//   stages (2 gll16): p=1: {A,B}(k+1)Q4 -> buf (k+1)%2
//                     p>=2: {A,B}(k+2)Q_{p-1} -> buf k%2
//   s_barrier ; setprio(1) ; 16 MFMA (m-frag pair {2p-2,2p-1} x 4 n x 2 ks)
//   setprio(0) ; [p=4: s_waitcnt vmcnt(6)] ; s_barrier
// Race proof: every LDS region is overwritten >=1 phase after its last read
// (A(k)Q_p read at phase p, A(k+2)Q_p staged at phase p+1; B(k) fully read at
// phase 1, B(k+2) staged phases 2-4; {k+1}Q4 goes to the other buffer), with a
// barrier between. vmcnt(6) at ph4 = exactly the 6 loads issued after
// B(k+1)Q4 -> tile k+1 fully resident before its phase 1; the "memory"
// clobber on that asm also fences compiler motion across buffers.
// Prologue primes the steady state: A0,B0 (8 loads), then {A,B}1 Q1..Q3
// (6 loads), vmcnt(6), barrier.
#define NKT 16          // CDIM/64 K-tiles
#define TBUF 32768      // shorts per buffer (A 16384 + B 16384)

__device__ __forceinline__ void gemm_core(
    const unsigned short* __restrict__ Aglob, const unsigned short* __restrict__ Bglob,
    unsigned short* smem, int m0, int n0, int tid, f4 (&acc)[8][4])
{
  const int lane = tid&63;
  const int g = lane>>4, c = lane&15;
  const int wv = tid>>6;
  const int wr = wv>>2, wcn = wv&3;

  // staging geometry: rloc=tid>>3 (0..63), cho=tid&7; source chunk pre-swizzled
  const int rloc = tid>>3, cho = tid&7;
  const int aside = (rloc>>5)<<7;              // 0 or 128
  const int ar = (rloc&31) + aside;            // A row within quarter (+q*32)
  const int schk = (cho ^ (rloc&7))*8;         // swizzled source chunk offset
  const unsigned short* aS = Aglob + (size_t)(m0+ar)*CDIM + schk;   // +q*32*CDIM +k2*64
  const unsigned short* bS = Bglob + (size_t)(n0+rloc)*CDIM + schk; // +q*64*CDIM +k2*64
  const int aD = ar*64 + cho*8;                // + q*2048 + buf*TBUF
  const int bD = 16384 + rloc*64 + cho*8;      // + q*4096 + buf*TBUF

#define STA(k2,q) gll16(aS + (size_t)(q)*32*CDIM + (k2)*64, smem + ((k2)&1)*TBUF + (q)*2048 + aD)
#define STB(k2,q) gll16(bS + (size_t)(q)*64*CDIM + (k2)*64, smem + ((k2)&1)*TBUF + (q)*4096 + bD)

  // fragment read offsets
  const int ch0 = (g ^ (c&7))*8;               // ks=0
  const int ch1 = ((4+g) ^ (c&7))*8;           // ks=1
  const int arow0 = (wr*128 + c)*64;           // + (2p+i)*1024
  const int brow0 = 16384 + (wcn*64 + c)*64;   // + nt*1024

  // ---- prologue: tile 0 full + tile 1 quarters 1..3 ----
#pragma unroll
  for (int q=0;q<4;q++) STA(0,q);
#pragma unroll
  for (int q=0;q<4;q++) STB(0,q);
#pragma unroll
  for (int q=0;q<3;q++){ STA(1,q); STB(1,q); }
  asm volatile("s_waitcnt vmcnt(6)" ::: "memory");   // tile 0 landed
  __builtin_amdgcn_s_barrier();

  for (int kt=0; kt<NKT; kt++){
    const unsigned short* bufA = smem + (kt&1)*TBUF;
    sh8 bfr[4][2];
#pragma unroll
    for (int p=0; p<4; p++){
      // reads: A-quarter p (+ all B at p==0)
      sh8 af[2][2];
#pragma unroll
      for (int i=0;i<2;i++){
        af[i][0] = *(const sh8*)(bufA + arow0 + (2*p+i)*1024 + ch0);
        af[i][1] = *(const sh8*)(bufA + arow0 + (2*p+i)*1024 + ch1);
      }
      if (p==0){
#pragma unroll
        for (int nt=0;nt<4;nt++){
          bfr[nt][0] = *(const sh8*)(bufA + brow0 + nt*1024 + ch0);
          bfr[nt][1] = *(const sh8*)(bufA + brow0 + nt*1024 + ch1);
        }
      }
      // stages
      if (p==0){
        if (kt+1 < NKT){ STA(kt+1,3); STB(kt+1,3); }
      } else {
        if (kt+2 < NKT){ STA(kt+2,p-1); STB(kt+2,p-1); }
      }
      __builtin_amdgcn_s_barrier();
      __builtin_amdgcn_s_setprio(1);
#pragma unroll
      for (int i=0;i<2;i++)
#pragma unroll
        for (int nt=0;nt<4;nt++){
          acc[2*p+i][nt] = __builtin_amdgcn_mfma_f32_16x16x32_bf16(af[i][0], bfr[nt][0], acc[2*p+i][nt],0,0,0);
          acc[2*p+i][nt] = __builtin_amdgcn_mfma_f32_16x16x32_bf16(af[i][1], bfr[nt][1], acc[2*p+i][nt],0,0,0);
        }
      __builtin_amdgcn_s_setprio(0);
      if (p==3){
        if (kt < NKT-2)       asm volatile("s_waitcnt vmcnt(6)" ::: "memory");
        else if (kt == NKT-2) asm volatile("s_waitcnt vmcnt(0)" ::: "memory");
      }
      __builtin_amdgcn_s_barrier();
    }
  }
#undef STA
#undef STB
}

// ---------------- final GEMM: C[m][n] = sum_k A[m][k]*W[n][k] + bias[n], fp32 out ----
__global__ __launch_bounds__(512,2) void gemm_u(
    const unsigned short* __restrict__ A, const unsigned short* __restrict__ Bw,
    const float* __restrict__ bias, float* __restrict__ Cout){
  __shared__ unsigned short smem[2*TBUF];
  const int tid  = threadIdx.x;
  const int lane = tid&63;
  const int g = lane>>4, c = lane&15;
  const int wv = tid>>6;
  const int wr = wv>>2, wcn = wv&3;
  const int m0 = blockIdx.x*256, n0 = blockIdx.y*256;
  f4 acc[8][4] = {};
  gemm_core(A, Bw, smem, m0, n0, tid, acc);

#pragma unroll
  for (int nt=0; nt<4; nt++){
    int nn = n0 + wcn*64 + nt*16 + c;
    float bsv = bias[nn];
#pragma unroll
    for (int mt=0; mt<8; mt++){
      int mb = m0 + wr*128 + mt*16 + 4*g;
#pragma unroll
      for (int r=0; r<4; r++)
        Cout[(size_t)(mb+r)*CDIM + nn] = acc[mt][nt][r] + bsv;
    }
  }
}

// ---------------- fused Q/K/V projection: blockIdx.z selects output ----------------
// z=0: Q = x1@Wq^T+bq, scaled by C2SCALE, bf16 row-major
// z=1: K = x2@Wk^T+bk, bf16 row-major
// z=2: V = x2@Wv^T+bv, bf16 transposed to (b,h,d,t)
__global__ __launch_bounds__(512,2) void gemm_qkv(
    const unsigned short* __restrict__ x1b, const unsigned short* __restrict__ x2b,
    const unsigned short* __restrict__ wq, const unsigned short* __restrict__ wk,
    const unsigned short* __restrict__ wv,
    const float* __restrict__ bq, const float* __restrict__ bk, const float* __restrict__ bv,
    unsigned short* __restrict__ Qo, unsigned short* __restrict__ Ko,
    unsigned short* __restrict__ Vo){
  __shared__ unsigned short smem[2*TBUF];
  const int z = blockIdx.z;
  const unsigned short* A  = (z==0) ? x1b : x2b;
  const unsigned short* Bw = (z==0) ? wq : (z==1) ? wk : wv;
  const float* bias        = (z==0) ? bq : (z==1) ? bk : bv;
  const int tid  = threadIdx.x;
  const int lane = tid&63;
  const int g = lane>>4, c = lane&15;
  const int wv2 = tid>>6;
  const int wr = wv2>>2, wcn = wv2&3;
  const int m0 = blockIdx.x*256, n0 = blockIdx.y*256;
  f4 acc[8][4] = {};
  gemm_core(A, Bw, smem, m0, n0, tid, acc);

#pragma unroll
  for (int nt=0; nt<4; nt++){
    int nn = n0 + wcn*64 + nt*16 + c;
    float bsv = bias[nn];
#pragma unroll
    for (int mt=0; mt<8; mt++){
      int mb = m0 + wr*128 + mt*16 + 4*g;
#pragma unroll
      for (int r=0; r<4; r++){
        float v = acc[mt][nt][r] + bsv;
        int mm = mb + r;
        if (z==0){
          Qo[(size_t)mm*CDIM + nn] = f2bf(v*C2SCALE);
        } else if (z==1){
          Ko[(size_t)mm*CDIM + nn] = f2bf(v);
        } else {
          int t = mm>>2, bb = mm&3, h = nn>>6, d = nn&63;
          Vo[(((size_t)bb*NH + h)*HD + d)*TSEQ + t] = f2bf(v);
        }
      }
    }
  }
}

// ---------------- flash attention, S^T / O^T (round-5 version, unchanged) -------
__global__ __launch_bounds__(256,4) void attn_kernel(
    const unsigned short* __restrict__ Q, const unsigned short* __restrict__ Kb,
    const unsigned short* __restrict__ Vt, unsigned short* __restrict__ O){
  __shared__ unsigned short Ks[2][64*64];      // (key, d), chunk ^= row&7
  __shared__ unsigned short Vs[2][64*64];      // (d, key), chunk ^= d&7
  const int tid=threadIdx.x, wave=tid>>6, lane=tid&63;
  const int g=lane>>4, c=lane&15;
  const bool godd = (g&1);
  const int gx = blockIdx.x;                   // 1024 linear blocks
  const int bh = ((gx>>7)<<3) | (gx&7);        // all 16 qts of a bh share gx%8 (same XCD)
  const int qt = (gx>>3)&15;
  const int b = bh>>4, h = bh&15;
  const int qbase = qt*128 + wave*32;

  // staging bases: per thread 2 gll16 for K, 2 for V, per 64-key tile
  const unsigned short* kb0[2];
  const unsigned short* vb0[2];
#pragma unroll
  for (int i=0; i<2; i++){
    int cc = i*256+tid;
    int krow = cc>>3, kch = (cc&7) ^ (krow&7);
    kb0[i] = Kb + ((size_t)krow*BB + b)*CDIM + h*HD + kch*8;
    int vd = cc>>3, vch = (cc&7) ^ (vd&7);
    vb0[i] = Vt + ((size_t)(b*NH+h)*HD + vd)*TSEQ + vch*8;
  }

  sh8 qfr[2][2];
#pragma unroll
  for (int qf=0; qf<2; qf++)
#pragma unroll
    for (int kc=0; kc<2; kc++){
      int t = qbase + qf*16 + c;
      qfr[qf][kc] = *(const sh8*)(Q + ((size_t)t*BB + b)*CDIM + h*HD + kc*32 + g*8);
    }

  f4 oacc[4][2] = {};                          // O^T frags: [d-frag][q-frag]
  float lrun[2] = {0.f, 0.f};                  // lane-local partial denominators

  // prologue: stage tile 0 into buffer 0
#pragma unroll
  for (int i=0; i<2; i++){
    gll16(kb0[i], Ks[0] + (i*256+tid)*8);
    gll16(vb0[i], Vs[0] + (i*256+tid)*8);
  }
  __syncthreads();                             // drains vmcnt(0): tile 0 resident

  const int NT = TSEQ/64;                      // 32 tiles
  int cur = 0;
  for (int it=0; it<NT; it++){
    if (it+1 < NT){
      int k0n = (it+1)*64;
#pragma unroll
      for (int i=0; i<2; i++){
        gll16(kb0[i] + (size_t)k0n*BB*CDIM, Ks[cur^1] + (i*256+tid)*8);
        gll16(vb0[i] + k0n,                 Vs[cur^1] + (i*256+tid)*8);
      }
    }
    const unsigned short* ks = Ks[cur];
    const unsigned short* vs = Vs[cur];

    // per 32-key group: S^T MFMA -> exp2 + in-register transpose -> PV MFMA
#pragma unroll
    for (int sub=0; sub<2; sub++){
      f4 sacc[2][2] = {};
      __builtin_amdgcn_s_setprio(1);
#pragma unroll
      for (int j=0; j<2; j++){
        int kf = sub*2 + j;
        sh8 af[2];
#pragma unroll
        for (int kc=0; kc<2; kc++){
          int ch = (kc*4+g) ^ (c&7);
          af[kc] = *(const sh8*)(ks + (kf*16+c)*64 + ch*8);
        }
#pragma unroll
        for (int kc=0; kc<2; kc++)
#pragma unroll
          for (int qf=0; qf<2; qf++)
            sacc[j][qf] = __builtin_amdgcn_mfma_f32_16x16x32_bf16(af[kc], qfr[qf][kc], sacc[j][qf],0,0,0);
      }
      __builtin_amdgcn_s_setprio(0);

      sh8 pf[2];
#pragma unroll
      for (int qf=0; qf<2; qf++){
        f4 sa = sacc[0][qf];
        f4 sb = sacc[1][qf];
        float pa0 = __builtin_amdgcn_exp2f(sa[0]);
        float pa1 = __builtin_amdgcn_exp2f(sa[1]);
        float pa2 = __builtin_amdgcn_exp2f(sa[2]);
        float pa3 = __builtin_amdgcn_exp2f(sa[3]);
        float pb0 = __builtin_amdgcn_exp2f(sb[0]);
        float pb1 = __builtin_amdgcn_exp2f(sb[1]);
        float pb2 = __builtin_amdgcn_exp2f(sb[2]);
        float pb3 = __builtin_amdgcn_exp2f(sb[3]);
        lrun[qf] += ((pa0+pa1)+(pa2+pa3)) + ((pb0+pb1)+(pb2+pb3));
        unsigned A0 = cvtpk(pa0, pa1);   // keys 4g+{0,1} of kf=sub*2
        unsigned A1 = cvtpk(pa2, pa3);   // keys 4g+{2,3}
        unsigned B0 = cvtpk(pb0, pb1);   // keys 4g+{0,1} of kf=sub*2+1
        unsigned B1 = cvtpk(pb2, pb3);
        asm("v_permlane32_swap_b32 %0, %1" : "+v"(A0), "+v"(B0));
        asm("v_permlane32_swap_b32 %0, %1" : "+v"(A1), "+v"(B1));
        unsigned xA0 = (unsigned)__builtin_amdgcn_ds_swizzle((int)A0, 0x401F);
        unsigned xA1 = (unsigned)__builtin_amdgcn_ds_swizzle((int)A1, 0x401F);
        unsigned xB0 = (unsigned)__builtin_amdgcn_ds_swizzle((int)B0, 0x401F);
        unsigned xB1 = (unsigned)__builtin_amdgcn_ds_swizzle((int)B1, 0x401F);
        u32x4 pw;
        pw.x = godd ? xB0 : A0;   // keys g*8+{0,1}
        pw.y = godd ? xB1 : A1;   // keys g*8+{2,3}
        pw.z = godd ? B0  : xA0;  // keys g*8+{4,5}
        pw.w = godd ? B1  : xA1;  // keys g*8+{6,7}
        pf[qf] = __builtin_bit_cast(sh8, pw);
      }
      __builtin_amdgcn_s_setprio(1);
#pragma unroll
      for (int df=0; df<4; df++){
        int ch = (sub*4+g) ^ (c&7);
        sh8 vf = *(const sh8*)(vs + (df*16+c)*64 + ch*8);
#pragma unroll
        for (int qf=0; qf<2; qf++)
          oacc[df][qf] = __builtin_amdgcn_mfma_f32_16x16x32_bf16(vf, pf[qf], oacc[df][qf],0,0,0);
      }
      __builtin_amdgcn_s_setprio(0);
    }

    __syncthreads();
    cur ^= 1;
  }

#pragma unroll
  for (int qf=0; qf<2; qf++){
    lrun[qf] += __shfl_xor(lrun[qf], 16, 64);
    lrun[qf] += __shfl_xor(lrun[qf], 32, 64);
    float inv = 1.0f/lrun[qf];
    int t = qbase + qf*16 + c;
#pragma unroll
    for (int df=0; df<4; df++){
      uint2 pr;
      pr.x = cvtpk(oacc[df][qf][0]*inv, oacc[df][qf][1]*inv);
      pr.y = cvtpk(oacc[df][qf][2]*inv, oacc[df][qf][3]*inv);
      *(uint2*)(O + ((size_t)b*TSEQ + t)*CDIM + h*HD + df*16 + 4*g) = pr;
    }
  }
}

extern "C" void kernel_launch(void* const* d_in, const int* in_sizes, int n_in,
                              void* d_out, int out_size, void* d_ws, size_t ws_size,
                              hipStream_t stream){
  (void)in_sizes; (void)n_in; (void)out_size; (void)ws_size;
  const float* x1 = (const float*)d_in[0];
  const float* x2 = (const float*)d_in[1];
  const float* Wq = (const float*)d_in[2];
  const float* bq = (const float*)d_in[3];
  const float* Wk = (const float*)d_in[4];
  const float* bk = (const float*)d_in[5];
  const float* Wv = (const float*)d_in[6];
  const float* bv = (const float*)d_in[7];
  const float* Wu = (const float*)d_in[8];
  const float* bu = (const float*)d_in[9];

  unsigned short* ws = (unsigned short*)d_ws;
  size_t o = 0;
  unsigned short* x1b = ws + o; o += (size_t)MR*CDIM;
  unsigned short* x2b = ws + o; o += (size_t)MR*CDIM;
  unsigned short* wqb = ws + o; o += (size_t)CDIM*CDIM;
  unsigned short* wkb = ws + o; o += (size_t)CDIM*CDIM;
  unsigned short* wvb = ws + o; o += (size_t)CDIM*CDIM;
  unsigned short* wub = ws + o; o += (size_t)CDIM*CDIM;
  unsigned short* Qb  = ws + o; o += (size_t)MR*CDIM;
  unsigned short* Kbf = ws + o; o += (size_t)MR*CDIM;
  unsigned short* Vtb = ws + o; o += (size_t)MR*CDIM;
  unsigned short* Ob  = x1b;   // x1b dead after QKV GEMM; reuse for attention output

  conv_x<<<dim3((MR*CDIM)/1024, 2),   256, 0, stream>>>(x1, x2, x1b, x2b);
  conv_w<<<dim3((CDIM*CDIM)/1024, 4), 256, 0, stream>>>(Wq, Wk, Wv, Wu, wqb, wkb, wvb, wub);

  gemm_qkv<<<dim3(MR/256, CDIM/256, 3), 512, 0, stream>>>(
      x1b, x2b, wqb, wkb, wvb, bq, bk, bv, Qb, Kbf, Vtb);
  attn_kernel<<<dim3(1024), 256, 0, stream>>>(Qb, Kbf, Vtb, Ob);
  gemm_u<<<dim3(MR/256, CDIM/256), 512, 0, stream>>>(Ob, wub, bu, (float*)d_out);
}

// Round 7
// 308.516 us; speedup vs baseline: 1.0806x; 1.0806x over previous
//
#include <hip/hip_runtime.h>

#define TSEQ 2048
#define BB 4
#define CDIM 1024
#define NH 16
#define HD 64
#define MR (TSEQ*BB)   // 8192 rows
#define C2SCALE 0.045084220f   // log2(e)/sqrt(CDIM) = log2(e)/32

typedef __attribute__((ext_vector_type(8))) short sh8;   // 8 bf16 = 4 VGPRs
typedef __attribute__((ext_vector_type(4))) short sh4;   // 4 bf16
typedef __attribute__((ext_vector_type(4))) float f4;    // MFMA C/D
typedef __attribute__((ext_vector_type(4))) unsigned int u32x4;

__device__ __forceinline__ unsigned short f2bf(float x){
  unsigned u = __builtin_bit_cast(unsigned, x);
  u += 0x7fffu + ((u>>16)&1u);          // round-to-nearest-even
  return (unsigned short)(u>>16);
}

// pack two floats -> dword of 2 bf16 (lo = a, hi = b), single VALU op
__device__ __forceinline__ unsigned cvtpk(float a, float b){
  unsigned r;
  asm("v_cvt_pk_bf16_f32 %0, %1, %2" : "=v"(r) : "v"(a), "v"(b));
  return r;
}

__device__ __forceinline__ void gll16(const unsigned short* g, unsigned short* l){
  __builtin_amdgcn_global_load_lds(
      (const __attribute__((address_space(1))) unsigned int*)g,
      (__attribute__((address_space(3))) unsigned int*)l, 16, 0, 0);
}

// ---------------- fp32 -> bf16 conversion, fused ----------------
__global__ void conv_x(const float* __restrict__ a, const float* __restrict__ b,
                       unsigned short* __restrict__ ya, unsigned short* __restrict__ yb){
  const float* s = blockIdx.y ? b : a;
  unsigned short* d = blockIdx.y ? yb : ya;
  int i = (blockIdx.x*256 + threadIdx.x)*4;
  f4 v = *(const f4*)(s+i);
  sh4 o;
  o.x = (short)f2bf(v.x); o.y = (short)f2bf(v.y);
  o.z = (short)f2bf(v.z); o.w = (short)f2bf(v.w);
  *(sh4*)(d+i) = o;
}

__global__ void conv_w(const float* __restrict__ w0, const float* __restrict__ w1,
                       const float* __restrict__ w2, const float* __restrict__ w3,
                       unsigned short* __restrict__ y0, unsigned short* __restrict__ y1,
                       unsigned short* __restrict__ y2, unsigned short* __restrict__ y3){
  const float* s; unsigned short* d;
  switch(blockIdx.y){
    case 0: s=w0; d=y0; break;
    case 1: s=w1; d=y1; break;
    case 2: s=w2; d=y2; break;
    default: s=w3; d=y3; break;
  }
  int i = (blockIdx.x*256 + threadIdx.x)*4;
  f4 v = *(const f4*)(s+i);
  sh4 o;
  o.x = (short)f2bf(v.x); o.y = (short)f2bf(v.y);
  o.z = (short)f2bf(v.z); o.w = (short)f2bf(v.w);
  *(sh4*)(d+i) = o;
}

// ============ round-4 GEMM core (for gemm_u): BM=256 BN=128, 4 waves ============
// Monolithic BK=64, 3-slot ring (144KB), prefetch 2 tiles ahead, vmcnt(12).
// Harness-verified in round 4. Per-round time measured 36us (768blk/3rounds/107us).
#define NKT4 16         // CDIM/64
#define BUFS4 24576     // shorts per ring slot (A 256*64=16384 + B 128*64=8192)

__device__ __forceinline__ void gemm_core4(
    const unsigned short* __restrict__ Aglob, const unsigned short* __restrict__ Bglob,
    unsigned short* smem, int m0, int n0, int tid, f4 (&acc)[8][4])
{
  const int wave = tid>>6, lane = tid&63;
  const int g = lane>>4, c = lane&15;
  const int wr = wave>>1, wc = wave&1;

  const int srow = tid>>3, sch = tid&7;
  const unsigned short* aBase = Aglob + (size_t)(m0+srow)*CDIM + (sch^(srow&7))*8;
  const unsigned short* bBase = Bglob + (size_t)(n0+srow)*CDIM + (sch^(srow&7))*8;

#pragma unroll
  for (int i=0;i<8;i++) gll16(aBase + (size_t)i*32*CDIM,      smem + (i*256+tid)*8);
#pragma unroll
  for (int i=0;i<4;i++) gll16(bBase + (size_t)i*32*CDIM,      smem + 16384 + (i*256+tid)*8);
#pragma unroll
  for (int i=0;i<8;i++) gll16(aBase + (size_t)i*32*CDIM + 64, smem + BUFS4 + (i*256+tid)*8);
#pragma unroll
  for (int i=0;i<4;i++) gll16(bBase + (size_t)i*32*CDIM + 64, smem + BUFS4 + 16384 + (i*256+tid)*8);
  asm volatile("s_waitcnt vmcnt(12)" ::: "memory");   // tile 0 landed
  __builtin_amdgcn_s_barrier();

  const int arow = wr*128 + c;
  const int brow = wc*64 + c;
  const int ch0 = g ^ (c&7);
  const int ch1 = (4+g) ^ (c&7);

  int q = 0;
  for (int kt=0; kt<NKT4; kt++){
    unsigned short* bufc = smem + q*BUFS4;
    int rr = q+2; if (rr>=3) rr-=3;
    unsigned short* dst = smem + rr*BUFS4;
    if (kt+2 < NKT4){
      const size_t koff = (size_t)(kt+2)*64;
#pragma unroll
      for (int i=0;i<8;i++) gll16(aBase + (size_t)i*32*CDIM + koff, dst + (i*256+tid)*8);
#pragma unroll
      for (int i=0;i<4;i++) gll16(bBase + (size_t)i*32*CDIM + koff, dst + 16384 + (i*256+tid)*8);
    }
    sh8 af[8][2], bfr[4][2];
#pragma unroll
    for (int mt=0;mt<8;mt++){
      af[mt][0] = *(const sh8*)(bufc + (arow+mt*16)*64 + ch0*8);
      af[mt][1] = *(const sh8*)(bufc + (arow+mt*16)*64 + ch1*8);
    }
#pragma unroll
    for (int nt=0;nt<4;nt++){
      bfr[nt][0] = *(const sh8*)(bufc + 16384 + (brow+nt*16)*64 + ch0*8);
      bfr[nt][1] = *(const sh8*)(bufc + 16384 + (brow+nt*16)*64 + ch1*8);
    }
    __builtin_amdgcn_s_setprio(1);
#pragma unroll
    for (int mt=0;mt<8;mt++)
#pragma unroll
      for (int nt=0;nt<4;nt++){
        acc[mt][nt] = __builtin_amdgcn_mfma_f32_16x16x32_bf16(af[mt][0], bfr[nt][0], acc[mt][nt],0,0,0);
        acc[mt][nt] = __builtin_amdgcn_mfma_f32_16x16x32_bf16(af[mt][1], bfr[nt][1], acc[mt][nt],0,0,0);
      }
    __builtin_amdgcn_s_setprio(0);
    if (kt < NKT4-1){
      if (kt < NKT4-2) asm volatile("s_waitcnt vmcnt(12)" ::: "memory");
      else             asm volatile("s_waitcnt vmcnt(0)" ::: "memory");
    }
    __builtin_amdgcn_s_barrier();
    q = (q==2)?0:q+1;
  }
}

// ---------------- final GEMM: round-4 version, grid (32,8) = 256 blocks --------
__global__ __launch_bounds__(256,1) void gemm_u(
    const unsigned short* __restrict__ A, const unsigned short* __restrict__ Bw,
    const float* __restrict__ bias, float* __restrict__ Cout){
  __shared__ unsigned short smem[3*BUFS4];
  const int tid  = threadIdx.x;
  const int wave = tid>>6, lane = tid&63;
  const int g = lane>>4, c = lane&15;
  const int m0 = blockIdx.x*256, n0 = blockIdx.y*128;
  const int wr = wave>>1, wc = wave&1;
  f4 acc[8][4] = {};
  gemm_core4(A, Bw, smem, m0, n0, tid, acc);

#pragma unroll
  for (int nt=0; nt<4; nt++){
    int nn = n0 + wc*64 + nt*16 + c;
    float bsv = bias[nn];
#pragma unroll
    for (int mt=0; mt<8; mt++){
      int mb = m0 + wr*128 + mt*16 + 4*g;
#pragma unroll
      for (int r=0; r<4; r++)
        Cout[(size_t)(mb+r)*CDIM + nn] = acc[mt][nt][r] + bsv;
    }
  }
}

// ============ m201-style 8-phase GEMM core (round-6, for gemm_qkv) ============
#define NKT 16          // CDIM/64 K-tiles
#define TBUF 32768      // shorts per buffer (A 16384 + B 16384)

__device__ __forceinline__ void gemm_core8(
    const unsigned short* __restrict__ Aglob, const unsigned short* __restrict__ Bglob,
    unsigned short* smem, int m0, int n0, int tid, f4 (&acc)[8][4])
{
  const int lane = tid&63;
  const int g = lane>>4, c = lane&15;
  const int wv = tid>>6;
  const int wr = wv>>2, wcn = wv&3;

  const int rloc = tid>>3, cho = tid&7;
  const int aside = (rloc>>5)<<7;
  const int ar = (rloc&31) + aside;
  const int schk = (cho ^ (rloc&7))*8;
  const unsigned short* aS = Aglob + (size_t)(m0+ar)*CDIM + schk;
  const unsigned short* bS = Bglob + (size_t)(n0+rloc)*CDIM + schk;
  const int aD = ar*64 + cho*8;
  const int bD = 16384 + rloc*64 + cho*8;

#define STA(k2,q) gll16(aS + (size_t)(q)*32*CDIM + (k2)*64, smem + ((k2)&1)*TBUF + (q)*2048 + aD)
#define STB(k2,q) gll16(bS + (size_t)(q)*64*CDIM + (k2)*64, smem + ((k2)&1)*TBUF + (q)*4096 + bD)

  const int ch0 = (g ^ (c&7))*8;
  const int ch1 = ((4+g) ^ (c&7))*8;
  const int arow0 = (wr*128 + c)*64;
  const int brow0 = 16384 + (wcn*64 + c)*64;

#pragma unroll
  for (int q=0;q<4;q++) STA(0,q);
#pragma unroll
  for (int q=0;q<4;q++) STB(0,q);
#pragma unroll
  for (int q=0;q<3;q++){ STA(1,q); STB(1,q); }
  asm volatile("s_waitcnt vmcnt(6)" ::: "memory");
  __builtin_amdgcn_s_barrier();

  for (int kt=0; kt<NKT; kt++){
    const unsigned short* bufA = smem + (kt&1)*TBUF;
    sh8 bfr[4][2];
#pragma unroll
    for (int p=0; p<4; p++){
      sh8 af[2][2];
#pragma unroll
      for (int i=0;i<2;i++){
        af[i][0] = *(const sh8*)(bufA + arow0 + (2*p+i)*1024 + ch0);
        af[i][1] = *(const sh8*)(bufA + arow0 + (2*p+i)*1024 + ch1);
      }
      if (p==0){
#pragma unroll
        for (int nt=0;nt<4;nt++){
          bfr[nt][0] = *(const sh8*)(bufA + brow0 + nt*1024 + ch0);
          bfr[nt][1] = *(const sh8*)(bufA + brow0 + nt*1024 + ch1);
        }
      }
      if (p==0){
        if (kt+1 < NKT){ STA(kt+1,3); STB(kt+1,3); }
      } else {
        if (kt+2 < NKT){ STA(kt+2,p-1); STB(kt+2,p-1); }
      }
      __builtin_amdgcn_s_barrier();
      __builtin_amdgcn_s_setprio(1);
#pragma unroll
      for (int i=0;i<2;i++)
#pragma unroll
        for (int nt=0;nt<4;nt++){
          acc[2*p+i][nt] = __builtin_amdgcn_mfma_f32_16x16x32_bf16(af[i][0], bfr[nt][0], acc[2*p+i][nt],0,0,0);
          acc[2*p+i][nt] = __builtin_amdgcn_mfma_f32_16x16x32_bf16(af[i][1], bfr[nt][1], acc[2*p+i][nt],0,0,0);
        }
      __builtin_amdgcn_s_setprio(0);
      if (p==3){
        if (kt < NKT-2)       asm volatile("s_waitcnt vmcnt(6)" ::: "memory");
        else if (kt == NKT-2) asm volatile("s_waitcnt vmcnt(0)" ::: "memory");
      }
      __builtin_amdgcn_s_barrier();
    }
  }
#undef STA
#undef STB
}

// ---------------- fused Q/K/V projection ----------------
// Round-7 change: z==2 (V) epilogue transposes the 256x256 output tile through
// the now-dead 128KB LDS so global writes are coalesced 128B runs along t
// (was: 128 scalar 2B stores/thread at 8B-useful-per-64B-line -> 46MB of
// write amplification, WRITE_SIZE 96MB vs 50MB useful).
// LDS layout: lv[nl*256 + bb*64 + (tloc ^ ((nl&7)<<3))]; the XOR avoids the
// 16-way write conflict (c-lanes at 512B stride). Read side un-XORs per-chunk:
// physical chunk j^key holds tloc j*8..j*8+7 in order (bijective per nl).
__global__ __launch_bounds__(512,2) void gemm_qkv(
    const unsigned short* __restrict__ x1b, const unsigned short* __restrict__ x2b,
    const unsigned short* __restrict__ wq, const unsigned short* __restrict__ wk,
    const unsigned short* __restrict__ wv,
    const float* __restrict__ bq, const float* __restrict__ bk, const float* __restrict__ bv,
    unsigned short* __restrict__ Qo, unsigned short* __restrict__ Ko,
    unsigned short* __restrict__ Vo){
  __shared__ unsigned short smem[2*TBUF];
  const int z = blockIdx.z;
  const unsigned short* A  = (z==0) ? x1b : x2b;
  const unsigned short* Bw = (z==0) ? wq : (z==1) ? wk : wv;
  const float* bias        = (z==0) ? bq : (z==1) ? bk : bv;
  const int tid  = threadIdx.x;
  const int lane = tid&63;
  const int g = lane>>4, c = lane&15;
  const int wv2 = tid>>6;
  const int wr = wv2>>2, wcn = wv2&3;
  const int m0 = blockIdx.x*256, n0 = blockIdx.y*256;
  f4 acc[8][4] = {};
  gemm_core8(A, Bw, smem, m0, n0, tid, acc);

  if (z != 2){
#pragma unroll
    for (int nt=0; nt<4; nt++){
      int nn = n0 + wcn*64 + nt*16 + c;
      float bsv = bias[nn];
#pragma unroll
      for (int mt=0; mt<8; mt++){
        int mb = m0 + wr*128 + mt*16 + 4*g;
#pragma unroll
        for (int r=0; r<4; r++){
          float v = acc[mt][nt][r] + bsv;
          int mm = mb + r;
          if (z==0) Qo[(size_t)mm*CDIM + nn] = f2bf(v*C2SCALE);
          else      Ko[(size_t)mm*CDIM + nn] = f2bf(v);
        }
      }
    }
  } else {
    // V transpose: gemm_core8's final barrier guarantees all LDS reads done.
    unsigned short* lv = smem;              // 65536 shorts = exactly the V tile
#pragma unroll
    for (int nt=0; nt<4; nt++){
      int nl = wcn*64 + nt*16 + c;          // nn_local (0..255)
      float bsv = bias[n0 + nl];
      int key = (nl&7)<<3;
#pragma unroll
      for (int mt=0; mt<8; mt++){
        int tl = wr*32 + mt*4 + g;          // tloc (0..63)
        int pos = nl*256 + (tl ^ key);
#pragma unroll
        for (int r=0; r<4; r++)
          lv[pos + r*64] = f2bf(acc[mt][nt][r] + bsv);
      }
    }
    __builtin_amdgcn_s_barrier();
    const int j = tid&7;
#pragma unroll
    for (int it=0; it<16; it++){
      int rid = it*64 + (tid>>3);           // 1024 rows = (nl, bb)
      int nl = rid>>2, bb = rid&3;
      sh8 vrow = *(const sh8*)(lv + nl*256 + bb*64 + ((j ^ (nl&7))<<3));
      int nn = n0 + nl; int h = nn>>6, d = nn&63;
      *(sh8*)(Vo + ((size_t)(bb*NH + h)*HD + d)*TSEQ + (m0>>2) + j*8) = vrow;
    }
  }
}

// ---------------- flash attention, S^T / O^T (round-5 version, unchanged) -------
__global__ __launch_bounds__(256,4) void attn_kernel(
    const unsigned short* __restrict__ Q, const unsigned short* __restrict__ Kb,
    const unsigned short* __restrict__ Vt, unsigned short* __restrict__ O){
  __shared__ unsigned short Ks[2][64*64];      // (key, d), chunk ^= row&7
  __shared__ unsigned short Vs[2][64*64];      // (d, key), chunk ^= d&7
  const int tid=threadIdx.x, wave=tid>>6, lane=tid&63;
  const int g=lane>>4, c=lane&15;
  const bool godd = (g&1);
  const int gx = blockIdx.x;                   // 1024 linear blocks
  const int bh = ((gx>>7)<<3) | (gx&7);        // all 16 qts of a bh share gx%8 (same XCD)
  const int qt = (gx>>3)&15;
  const int b = bh>>4, h = bh&15;
  const int qbase = qt*128 + wave*32;

  const unsigned short* kb0[2];
  const unsigned short* vb0[2];
#pragma unroll
  for (int i=0; i<2; i++){
    int cc = i*256+tid;
    int krow = cc>>3, kch = (cc&7) ^ (krow&7);
    kb0[i] = Kb + ((size_t)krow*BB + b)*CDIM + h*HD + kch*8;
    int vd = cc>>3, vch = (cc&7) ^ (vd&7);
    vb0[i] = Vt + ((size_t)(b*NH+h)*HD + vd)*TSEQ + vch*8;
  }

  sh8 qfr[2][2];
#pragma unroll
  for (int qf=0; qf<2; qf++)
#pragma unroll
    for (int kc=0; kc<2; kc++){
      int t = qbase + qf*16 + c;
      qfr[qf][kc] = *(const sh8*)(Q + ((size_t)t*BB + b)*CDIM + h*HD + kc*32 + g*8);
    }

  f4 oacc[4][2] = {};
  float lrun[2] = {0.f, 0.f};

#pragma unroll
  for (int i=0; i<2; i++){
    gll16(kb0[i], Ks[0] + (i*256+tid)*8);
    gll16(vb0[i], Vs[0] + (i*256+tid)*8);
  }
  __syncthreads();

  const int NT = TSEQ/64;
  int cur = 0;
  for (int it=0; it<NT; it++){
    if (it+1 < NT){
      int k0n = (it+1)*64;
#pragma unroll
      for (int i=0; i<2; i++){
        gll16(kb0[i] + (size_t)k0n*BB*CDIM, Ks[cur^1] + (i*256+tid)*8);
        gll16(vb0[i] + k0n,                 Vs[cur^1] + (i*256+tid)*8);
      }
    }
    const unsigned short* ks = Ks[cur];
    const unsigned short* vs = Vs[cur];

#pragma unroll
    for (int sub=0; sub<2; sub++){
      f4 sacc[2][2] = {};
      __builtin_amdgcn_s_setprio(1);
#pragma unroll
      for (int j=0; j<2; j++){
        int kf = sub*2 + j;
        sh8 af[2];
#pragma unroll
        for (int kc=0; kc<2; kc++){
          int ch = (kc*4+g) ^ (c&7);
          af[kc] = *(const sh8*)(ks + (kf*16+c)*64 + ch*8);
        }
#pragma unroll
        for (int kc=0; kc<2; kc++)
#pragma unroll
          for (int qf=0; qf<2; qf++)
            sacc[j][qf] = __builtin_amdgcn_mfma_f32_16x16x32_bf16(af[kc], qfr[qf][kc], sacc[j][qf],0,0,0);
      }
      __builtin_amdgcn_s_setprio(0);

      sh8 pf[2];
#pragma unroll
      for (int qf=0; qf<2; qf++){
        f4 sa = sacc[0][qf];
        f4 sb = sacc[1][qf];
        float pa0 = __builtin_amdgcn_exp2f(sa[0]);
        float pa1 = __builtin_amdgcn_exp2f(sa[1]);
        float pa2 = __builtin_amdgcn_exp2f(sa[2]);
        float pa3 = __builtin_amdgcn_exp2f(sa[3]);
        float pb0 = __builtin_amdgcn_exp2f(sb[0]);
        float pb1 = __builtin_amdgcn_exp2f(sb[1]);
        float pb2 = __builtin_amdgcn_exp2f(sb[2]);
        float pb3 = __builtin_amdgcn_exp2f(sb[3]);
        lrun[qf] += ((pa0+pa1)+(pa2+pa3)) + ((pb0+pb1)+(pb2+pb3));
        unsigned A0 = cvtpk(pa0, pa1);
        unsigned A1 = cvtpk(pa2, pa3);
        unsigned B0 = cvtpk(pb0, pb1);
        unsigned B1 = cvtpk(pb2, pb3);
        asm("v_permlane32_swap_b32 %0, %1" : "+v"(A0), "+v"(B0));
        asm("v_permlane32_swap_b32 %0, %1" : "+v"(A1), "+v"(B1));
        unsigned xA0 = (unsigned)__builtin_amdgcn_ds_swizzle((int)A0, 0x401F);
        unsigned xA1 = (unsigned)__builtin_amdgcn_ds_swizzle((int)A1, 0x401F);
        unsigned xB0 = (unsigned)__builtin_amdgcn_ds_swizzle((int)B0, 0x401F);
        unsigned xB1 = (unsigned)__builtin_amdgcn_ds_swizzle((int)B1, 0x401F);
        u32x4 pw;
        pw.x = godd ? xB0 : A0;
        pw.y = godd ? xB1 : A1;
        pw.z = godd ? B0  : xA0;
        pw.w = godd ? B1  : xA1;
        pf[qf] = __builtin_bit_cast(sh8, pw);
      }
      __builtin_amdgcn_s_setprio(1);
#pragma unroll
      for (int df=0; df<4; df++){
        int ch = (sub*4+g) ^ (c&7);
        sh8 vf = *(const sh8*)(vs + (df*16+c)*64 + ch*8);
#pragma unroll
        for (int qf=0; qf<2; qf++)
          oacc[df][qf] = __builtin_amdgcn_mfma_f32_16x16x32_bf16(vf, pf[qf], oacc[df][qf],0,0,0);
      }
      __builtin_amdgcn_s_setprio(0);
    }

    __syncthreads();
    cur ^= 1;
  }

#pragma unroll
  for (int qf=0; qf<2; qf++){
    lrun[qf] += __shfl_xor(lrun[qf], 16, 64);
    lrun[qf] += __shfl_xor(lrun[qf], 32, 64);
    float inv = 1.0f/lrun[qf];
    int t = qbase + qf*16 + c;
#pragma unroll
    for (int df=0; df<4; df++){
      uint2 pr;
      pr.x = cvtpk(oacc[df][qf][0]*inv, oacc[df][qf][1]*inv);
      pr.y = cvtpk(oacc[df][qf][2]*inv, oacc[df][qf][3]*inv);
      *(uint2*)(O + ((size_t)b*TSEQ + t)*CDIM + h*HD + df*16 + 4*g) = pr;
    }
  }
}

extern "C" void kernel_launch(void* const* d_in, const int* in_sizes, int n_in,
                              void* d_out, int out_size, void* d_ws, size_t ws_size,
                              hipStream_t stream){
  (void)in_sizes; (void)n_in; (void)out_size; (void)ws_size;
  const float* x1 = (const float*)d_in[0];
  const float* x2 = (const float*)d_in[1];
  const float* Wq = (const float*)d_in[2];
  const float* bq = (const float*)d_in[3];
  const float* Wk = (const float*)d_in[4];
  const float* bk = (const float*)d_in[5];
  const float* Wv = (const float*)d_in[6];
  const float* bv = (const float*)d_in[7];
  const float* Wu = (const float*)d_in[8];
  const float* bu = (const float*)d_in[9];

  unsigned short* ws = (unsigned short*)d_ws;
  size_t o = 0;
  unsigned short* x1b = ws + o; o += (size_t)MR*CDIM;
  unsigned short* x2b = ws + o; o += (size_t)MR*CDIM;
  unsigned short* wqb = ws + o; o += (size_t)CDIM*CDIM;
  unsigned short* wkb = ws + o; o += (size_t)CDIM*CDIM;
  unsigned short* wvb = ws + o; o += (size_t)CDIM*CDIM;
  unsigned short* wub = ws + o; o += (size_t)CDIM*CDIM;
  unsigned short* Qb  = ws + o; o += (size_t)MR*CDIM;
  unsigned short* Kbf = ws + o; o += (size_t)MR*CDIM;
  unsigned short* Vtb = ws + o; o += (size_t)MR*CDIM;
  unsigned short* Ob  = x1b;   // x1b dead after QKV GEMM; reuse for attention output

  conv_x<<<dim3((MR*CDIM)/1024, 2),   256, 0, stream>>>(x1, x2, x1b, x2b);
  conv_w<<<dim3((CDIM*CDIM)/1024, 4), 256, 0, stream>>>(Wq, Wk, Wv, Wu, wqb, wkb, wvb, wub);

  gemm_qkv<<<dim3(MR/256, CDIM/256, 3), 512, 0, stream>>>(
      x1b, x2b, wqb, wkb, wvb, bq, bk, bv, Qb, Kbf, Vtb);
  attn_kernel<<<dim3(1024), 256, 0, stream>>>(Qb, Kbf, Vtb, Ob);
  gemm_u<<<dim3(MR/256, CDIM/128), 256, 0, stream>>>(Ob, wub, bu, (float*)d_out);
}